// Round 1
// baseline (6279.195 us; speedup 1.0000x reference)
//
#include <hip/hip_runtime.h>
#include <cstdint>

typedef __bf16 bf16;
typedef __bf16 bf16x8 __attribute__((ext_vector_type(8)));
typedef __bf16 bf16x4 __attribute__((ext_vector_type(4)));
typedef float f32x4 __attribute__((ext_vector_type(4)));

static_assert(sizeof(bf16) == 2, "bf16 size");

constexpr int LAYERS = 6;
constexpr int BATCH  = 8;
constexpr int TDEC   = 1024;
constexpr int SENC   = 1024;
constexpr int EMB    = 1024;
constexpr int NH     = 16;
constexpr int FFN    = 4096;
constexpr int MTOK   = BATCH * TDEC;  // 8192

typedef __attribute__((address_space(1))) void gvoid;
typedef __attribute__((address_space(3))) void lvoid;

// async global->LDS, 16B per lane; LDS dest = wave-uniform base + lane*16
__device__ __forceinline__ void gload16(const void* g, void* l) {
  __builtin_amdgcn_global_load_lds((gvoid*)(uintptr_t)g,
                                   (lvoid*)(uint32_t)(uintptr_t)l,
                                   16, 0, 0);
}

__device__ __forceinline__ f32x4 mfma_16x16x32(bf16x8 a, bf16x8 b, f32x4 c) {
  return __builtin_amdgcn_mfma_f32_16x16x32_bf16(a, b, c, 0, 0, 0);
}

// ---------------- elementwise: fp32 -> bf16 convert ----------------
__global__ void k_cvt(const float* __restrict__ in, bf16* __restrict__ outp, int n4) {
  int i = blockIdx.x * 256 + threadIdx.x;
  if (i < n4) {
    float4 v = ((const float4*)in)[i];
    bf16x4 o;
    o[0] = (bf16)v.x; o[1] = (bf16)v.y; o[2] = (bf16)v.z; o[3] = (bf16)v.w;
    ((bf16x4*)outp)[i] = o;
  }
}

// ---------------- transpose fp32 [R,C] -> bf16 [C,R] ----------------
__launch_bounds__(256)
__global__ void k_transpose(const float* __restrict__ in, bf16* __restrict__ outp,
                            int R, int C) {
  __shared__ float tile[32][33];
  const int tx = threadIdx.x, ty = threadIdx.y;
  const int r0 = blockIdx.y * 32, c0 = blockIdx.x * 32;
#pragma unroll
  for (int i = 0; i < 32; i += 8)
    tile[ty + i][tx] = in[(size_t)(r0 + ty + i) * C + c0 + tx];
  __syncthreads();
#pragma unroll
  for (int i = 0; i < 32; i += 8)
    outp[(size_t)(c0 + ty + i) * R + r0 + tx] = (bf16)tile[tx][ty + i];
}

// ---------------- LayerNorm fp32 -> bf16, row = 1024 ----------------
__launch_bounds__(256)
__global__ void k_layernorm(const float* __restrict__ x, const float* __restrict__ w,
                            const float* __restrict__ bb, bf16* __restrict__ outp) {
  const int row = blockIdx.x;
  const int t = threadIdx.x;
  const float4 v = ((const float4*)(x + (size_t)row * EMB))[t];
  float s = v.x + v.y + v.z + v.w;
  __shared__ float red[4];
#pragma unroll
  for (int off = 32; off > 0; off >>= 1) s += __shfl_down(s, off, 64);
  if ((t & 63) == 0) red[t >> 6] = s;
  __syncthreads();
  const float mean = (red[0] + red[1] + red[2] + red[3]) * (1.0f / EMB);
  const float dx = v.x - mean, dy = v.y - mean, dz = v.z - mean, dw = v.w - mean;
  float ss = dx * dx + dy * dy + dz * dz + dw * dw;
  __syncthreads();
#pragma unroll
  for (int off = 32; off > 0; off >>= 1) ss += __shfl_down(ss, off, 64);
  if ((t & 63) == 0) red[t >> 6] = ss;
  __syncthreads();
  const float var = (red[0] + red[1] + red[2] + red[3]) * (1.0f / EMB);
  const float rstd = rsqrtf(var + 1e-5f);
  const float4 wv = ((const float4*)w)[t];
  const float4 bv = ((const float4*)bb)[t];
  bf16x4 o;
  o[0] = (bf16)(dx * rstd * wv.x + bv.x);
  o[1] = (bf16)(dy * rstd * wv.y + bv.y);
  o[2] = (bf16)(dz * rstd * wv.z + bv.z);
  o[3] = (bf16)(dw * rstd * wv.w + bv.w);
  *(bf16x4*)(outp + (size_t)row * EMB + t * 4) = o;
}

// ---------------- GEMM: C[M,N] = A[M,K] @ Bt[N,K]^T ----------------
// EPI 0: bf16 out. EPI 1: bf16 out = gelu(acc + bias). EPI 2: fp32 out = res + acc + bias.
template <int EPI>
__launch_bounds__(256)
__global__ void k_gemm(const bf16* __restrict__ A, const bf16* __restrict__ Bt,
                       int M, int N, int K,
                       bf16* __restrict__ outb, float* __restrict__ outf,
                       const float* __restrict__ res, const float* __restrict__ bias) {
  __shared__ __align__(16) bf16 sA[128 * 32];
  __shared__ __align__(16) bf16 sB[128 * 32];
  const int tid = threadIdx.x;
  const int wave = tid >> 6, lane = tid & 63;
  const int quad = lane >> 4, l16 = lane & 15;
  const int wm = wave >> 1, wn = wave & 1;
  const int bm = blockIdx.y, bn = blockIdx.x;

  f32x4 acc[4][4] = {};

  const int srow = wave * 16 + (lane >> 2);
  const int scol = (lane & 3) * 8;
  const bf16* Ag = A  + (size_t)(bm * 128 + srow) * K + scol;
  const bf16* Bg = Bt + (size_t)(bn * 128 + srow) * K + scol;
  bf16* sA0 = &sA[(wave * 16) * 32];
  bf16* sA1 = &sA[(wave * 16 + 64) * 32];
  bf16* sB0 = &sB[(wave * 16) * 32];
  bf16* sB1 = &sB[(wave * 16 + 64) * 32];

  const int nk = K >> 5;
  for (int kt = 0; kt < nk; ++kt) {
    gload16(Ag, sA0);
    gload16(Ag + (size_t)64 * K, sA1);
    gload16(Bg, sB0);
    gload16(Bg + (size_t)64 * K, sB1);
    Ag += 32; Bg += 32;
    __syncthreads();
    bf16x8 af[4], bfv[4];
    const bf16* pa = &sA[(wm * 64 + l16) * 32 + quad * 8];
    const bf16* pb = &sB[(wn * 64 + l16) * 32 + quad * 8];
#pragma unroll
    for (int i = 0; i < 4; ++i) af[i] = *(const bf16x8*)(pa + i * 16 * 32);
#pragma unroll
    for (int i = 0; i < 4; ++i) bfv[i] = *(const bf16x8*)(pb + i * 16 * 32);
#pragma unroll
    for (int i = 0; i < 4; ++i)
#pragma unroll
      for (int j = 0; j < 4; ++j)
        acc[i][j] = mfma_16x16x32(af[i], bfv[j], acc[i][j]);
    __syncthreads();
  }

  const int row0 = bm * 128 + wm * 64;
  const int col0 = bn * 128 + wn * 64;
#pragma unroll
  for (int j = 0; j < 4; ++j) {
    const int c = col0 + j * 16 + l16;
    const float bv = (EPI >= 1) ? bias[c] : 0.0f;
#pragma unroll
    for (int i = 0; i < 4; ++i) {
#pragma unroll
      for (int r = 0; r < 4; ++r) {
        const size_t rr = (size_t)(row0 + i * 16 + quad * 4 + r);
        float v = acc[i][j][r];
        if (EPI == 0) {
          outb[rr * N + c] = (bf16)v;
        } else if (EPI == 1) {
          v += bv;
          const float g = 0.5f * v *
              (1.0f + tanhf(0.7978845608028654f * (v + 0.044715f * v * v * v)));
          outb[rr * N + c] = (bf16)g;
        } else {
          outf[rr * N + c] = res[rr * N + c] + v + bv;
        }
      }
    }
  }
}

// ---------------- flash attention ----------------
// Q [B,TQ,E], K/V [B,TK,E] (head h occupies cols h*64..h*64+63), out [B,TQ,E]
// grid: (TQ/64, B*NH), block 256. Wave w handles q rows q0+16w..+15.
template <bool CAUSAL>
__launch_bounds__(256)
__global__ void k_attn(const bf16* __restrict__ Q, const bf16* __restrict__ Kg,
                       const bf16* __restrict__ Vg, bf16* __restrict__ Og,
                       int TQ, int TK) {
  __shared__ __align__(16) bf16 sK[32 * 64];
  __shared__ __align__(16) bf16 sVt[64 * 32];
  __shared__ __align__(16) bf16 sP[4][16 * 32];
  const int tid = threadIdx.x;
  const int wave = tid >> 6, lane = tid & 63;
  const int quad = lane >> 4, l16 = lane & 15;
  const int b = blockIdx.y >> 4;   // NH == 16
  const int h = blockIdx.y & 15;
  const int q0 = blockIdx.x * 64;
  const int qw = q0 + wave * 16;

  const bf16* qp = Q + (size_t)(b * TQ + qw + l16) * EMB + h * 64 + quad * 8;
  const bf16x8 aq0 = *(const bf16x8*)(qp);
  const bf16x8 aq1 = *(const bf16x8*)(qp + 32);

  f32x4 oacc[4] = {};
  float m_[4], l_[4];
#pragma unroll
  for (int r = 0; r < 4; ++r) { m_[r] = -1e30f; l_[r] = 0.0f; }

  const int krow = tid >> 3;            // 0..31
  const int kcol = (tid & 7) * 8;       // 0..56
  const bf16* Kp = Kg + (size_t)(b * TK + krow) * EMB + h * 64 + kcol;
  const bf16* Vp = Vg + (size_t)(b * TK + krow) * EMB + h * 64 + kcol;
  bf16* sKw = &sK[wave * 512];

  const float sc = 0.125f * 1.44269504088896f;  // 1/sqrt(64) * log2(e)
  const int nj = CAUSAL ? (q0 / 32 + 2) : (TK / 32);

  for (int j = 0; j < nj; ++j) {
    gload16(Kp, sKw);
    const bf16x8 vv = *(const bf16x8*)(Vp);
#pragma unroll
    for (int e = 0; e < 8; ++e) sVt[(kcol + e) * 32 + krow] = vv[e];
    Kp += (size_t)32 * EMB;
    Vp += (size_t)32 * EMB;
    __syncthreads();
    const bool active = !CAUSAL || (j * 32 <= qw + 15);
    if (active) {
      f32x4 sacc[2];
#pragma unroll
      for (int kt = 0; kt < 2; ++kt) {
        const bf16* kp = &sK[(kt * 16 + l16) * 64 + quad * 8];
        f32x4 z = {};
        z = mfma_16x16x32(aq0, *(const bf16x8*)(kp), z);
        z = mfma_16x16x32(aq1, *(const bf16x8*)(kp + 32), z);
        sacc[kt] = z;
      }
      float rowmax[4] = {-1e30f, -1e30f, -1e30f, -1e30f};
#pragma unroll
      for (int kt = 0; kt < 2; ++kt) {
        const int key = j * 32 + kt * 16 + l16;
#pragma unroll
        for (int r = 0; r < 4; ++r) {
          float tv = sacc[kt][r] * sc;
          if (CAUSAL && key > qw + quad * 4 + r) tv = -1e30f;
          sacc[kt][r] = tv;
          rowmax[r] = fmaxf(rowmax[r], tv);
        }
      }
#pragma unroll
      for (int off = 1; off < 16; off <<= 1)
#pragma unroll
        for (int r = 0; r < 4; ++r)
          rowmax[r] = fmaxf(rowmax[r], __shfl_xor(rowmax[r], off, 64));
      float alpha[4], rs[4];
#pragma unroll
      for (int r = 0; r < 4; ++r) {
        const float mn = fmaxf(m_[r], rowmax[r]);
        alpha[r] = exp2f(m_[r] - mn);
        m_[r] = mn;
        rs[r] = 0.0f;
      }
#pragma unroll
      for (int kt = 0; kt < 2; ++kt)
#pragma unroll
        for (int r = 0; r < 4; ++r) {
          const float pv = exp2f(sacc[kt][r] - m_[r]);
          sacc[kt][r] = pv;
          rs[r] += pv;
        }
#pragma unroll
      for (int off = 1; off < 16; off <<= 1)
#pragma unroll
        for (int r = 0; r < 4; ++r)
          rs[r] += __shfl_xor(rs[r], off, 64);
#pragma unroll
      for (int r = 0; r < 4; ++r) {
        l_[r] = l_[r] * alpha[r] + rs[r];
#pragma unroll
        for (int dt = 0; dt < 4; ++dt) oacc[dt][r] *= alpha[r];
      }
      // P (C-layout) -> LDS -> A-layout
#pragma unroll
      for (int kt = 0; kt < 2; ++kt)
#pragma unroll
        for (int r = 0; r < 4; ++r)
          sP[wave][(quad * 4 + r) * 32 + kt * 16 + l16] = (bf16)sacc[kt][r];
    }
    __syncthreads();
    if (active) {
      const bf16x8 ap = *(const bf16x8*)(&sP[wave][l16 * 32 + quad * 8]);
#pragma unroll
      for (int dt = 0; dt < 4; ++dt) {
        const bf16x8 bv = *(const bf16x8*)(&sVt[(dt * 16 + l16) * 32 + quad * 8]);
        oacc[dt] = mfma_16x16x32(ap, bv, oacc[dt]);
      }
    }
    __syncthreads();
  }
#pragma unroll
  for (int r = 0; r < 4; ++r) {
    const float inv = 1.0f / l_[r];
    bf16* op = Og + (size_t)(b * TQ + qw + quad * 4 + r) * EMB + h * 64;
#pragma unroll
    for (int dt = 0; dt < 4; ++dt)
      op[dt * 16 + l16] = (bf16)(oacc[dt][r] * inv);
  }
}

// ---------------- host orchestration ----------------
extern "C" void kernel_launch(void* const* d_in, const int* in_sizes, int n_in,
                              void* d_out, int out_size, void* d_ws, size_t ws_size,
                              hipStream_t stream) {
  const float* enc  = (const float*)d_in[0];
  const float* dec  = (const float*)d_in[1];
  const float* ln1w = (const float*)d_in[2];
  const float* ln1b = (const float*)d_in[3];
  const float* ln2w = (const float*)d_in[4];
  const float* ln2b = (const float*)d_in[5];
  const float* ln3w = (const float*)d_in[6];
  const float* ln3b = (const float*)d_in[7];
  const float* Wq_s = (const float*)d_in[8];
  const float* Wk_s = (const float*)d_in[9];
  const float* Wv_s = (const float*)d_in[10];
  const float* Wo_s = (const float*)d_in[11];
  const float* bo_s = (const float*)d_in[12];
  const float* Wq_c = (const float*)d_in[13];
  const float* Wk_c = (const float*)d_in[14];
  const float* Wv_c = (const float*)d_in[15];
  const float* Wo_c = (const float*)d_in[16];
  const float* bo_c = (const float*)d_in[17];
  const float* W1   = (const float*)d_in[18];
  const float* b1   = (const float*)d_in[19];
  const float* W2   = (const float*)d_in[20];
  const float* b2   = (const float*)d_in[21];
  float* out = (float*)d_out;

  char* p = (char*)d_ws;
  auto take = [&](size_t bytes) {
    char* r = p;
    p += (bytes + 255) & ~(size_t)255;
    return (void*)r;
  };
  bf16* wqT  = (bf16*)take((size_t)EMB * EMB * 2);
  bf16* wkT  = (bf16*)take((size_t)EMB * EMB * 2);
  bf16* wvT  = (bf16*)take((size_t)EMB * EMB * 2);
  bf16* woT  = (bf16*)take((size_t)EMB * EMB * 2);
  bf16* w1T  = (bf16*)take((size_t)EMB * FFN * 2);
  bf16* w2T  = (bf16*)take((size_t)FFN * EMB * 2);
  bf16* encb = (bf16*)take((size_t)BATCH * SENC * EMB * 2);
  float* xbuf = (float*)take((size_t)MTOK * EMB * 4);
  bf16* nx = (bf16*)take((size_t)MTOK * EMB * 2);
  bf16* qb = (bf16*)take((size_t)MTOK * EMB * 2);
  bf16* kb = (bf16*)take((size_t)MTOK * EMB * 2);
  bf16* vb = (bf16*)take((size_t)MTOK * EMB * 2);
  bf16* ab = (bf16*)take((size_t)MTOK * EMB * 2);
  bf16* hb = (bf16*)take((size_t)MTOK * FFN * 2);
  if ((size_t)((char*)p - (char*)d_ws) > ws_size) return;  // ws too small: fail loudly

  // encoder -> bf16 (once); x = decoder_input
  {
    const int n4 = BATCH * SENC * EMB / 4;
    k_cvt<<<(n4 + 255) / 256, 256, 0, stream>>>(enc, encb, n4);
  }
  hipMemcpyAsync(xbuf, dec, (size_t)MTOK * EMB * 4, hipMemcpyDeviceToDevice, stream);

  auto trans = [&](const float* w, bf16* wt, int R, int C) {
    k_transpose<<<dim3(C / 32, R / 32), dim3(32, 8), 0, stream>>>(w, wt, R, C);
  };
  auto gemm0 = [&](const bf16* Ap, const bf16* Btp, bf16* op, int M, int N, int K) {
    k_gemm<0><<<dim3(N / 128, M / 128), 256, 0, stream>>>(Ap, Btp, M, N, K, op,
                                                          nullptr, nullptr, nullptr);
  };
  auto gemm_gelu = [&](const bf16* Ap, const bf16* Btp, bf16* op, const float* bi,
                       int M, int N, int K) {
    k_gemm<1><<<dim3(N / 128, M / 128), 256, 0, stream>>>(Ap, Btp, M, N, K, op,
                                                          nullptr, nullptr, bi);
  };
  auto gemm_res = [&](const bf16* Ap, const bf16* Btp, float* op, const float* rs,
                      const float* bi, int M, int N, int K) {
    k_gemm<2><<<dim3(N / 128, M / 128), 256, 0, stream>>>(Ap, Btp, M, N, K, nullptr,
                                                          op, rs, bi);
  };

  for (int l = 0; l < LAYERS; ++l) {
    const size_t wofs = (size_t)l * EMB * EMB;
    // ---- self attention ----
    k_layernorm<<<MTOK, 256, 0, stream>>>(xbuf, ln1w + l * EMB, ln1b + l * EMB, nx);
    trans(Wq_s + wofs, wqT, EMB, EMB);
    trans(Wk_s + wofs, wkT, EMB, EMB);
    trans(Wv_s + wofs, wvT, EMB, EMB);
    trans(Wo_s + wofs, woT, EMB, EMB);
    gemm0(nx, wqT, qb, MTOK, EMB, EMB);
    gemm0(nx, wkT, kb, MTOK, EMB, EMB);
    gemm0(nx, wvT, vb, MTOK, EMB, EMB);
    k_attn<true><<<dim3(TDEC / 64, BATCH * NH), 256, 0, stream>>>(qb, kb, vb, ab,
                                                                  TDEC, TDEC);
    gemm_res(ab, woT, xbuf, xbuf, bo_s + l * EMB, MTOK, EMB, EMB);

    // ---- cross attention ----
    k_layernorm<<<MTOK, 256, 0, stream>>>(xbuf, ln2w + l * EMB, ln2b + l * EMB, nx);
    trans(Wq_c + wofs, wqT, EMB, EMB);
    trans(Wk_c + wofs, wkT, EMB, EMB);
    trans(Wv_c + wofs, wvT, EMB, EMB);
    trans(Wo_c + wofs, woT, EMB, EMB);
    gemm0(nx, wqT, qb, MTOK, EMB, EMB);
    gemm0(encb, wkT, kb, BATCH * SENC, EMB, EMB);
    gemm0(encb, wvT, vb, BATCH * SENC, EMB, EMB);
    k_attn<false><<<dim3(TDEC / 64, BATCH * NH), 256, 0, stream>>>(qb, kb, vb, ab,
                                                                   TDEC, SENC);
    gemm_res(ab, woT, xbuf, xbuf, bo_c + l * EMB, MTOK, EMB, EMB);

    // ---- FFN ----
    k_layernorm<<<MTOK, 256, 0, stream>>>(xbuf, ln3w + l * EMB, ln3b + l * EMB, nx);
    trans(W1 + (size_t)l * EMB * FFN, w1T, EMB, FFN);
    trans(W2 + (size_t)l * FFN * EMB, w2T, FFN, EMB);
    gemm_gelu(nx, w1T, hb, b1 + (size_t)l * FFN, MTOK, FFN, EMB);
    float* fout = (l == LAYERS - 1) ? out : xbuf;
    gemm_res(hb, w2T, fout, xbuf, b2 + (size_t)l * EMB, MTOK, EMB, FFN);
  }
}

// Round 2
// 5289.054 us; speedup vs baseline: 1.1872x; 1.1872x over previous
//
#include <hip/hip_runtime.h>
#include <cstdint>

typedef __bf16 bf16;
typedef __bf16 bf16x8 __attribute__((ext_vector_type(8)));
typedef __bf16 bf16x4 __attribute__((ext_vector_type(4)));
typedef float f32x4 __attribute__((ext_vector_type(4)));

static_assert(sizeof(bf16) == 2, "bf16 size");

constexpr int LAYERS = 6;
constexpr int BATCH  = 8;
constexpr int TDEC   = 1024;
constexpr int SENC   = 1024;
constexpr int EMB    = 1024;
constexpr int NH     = 16;
constexpr int FFN    = 4096;
constexpr int MTOK   = BATCH * TDEC;  // 8192

typedef __attribute__((address_space(1))) void gvoid;
typedef __attribute__((address_space(3))) void lvoid;

// async global->LDS, 16B per lane; LDS dest = wave-uniform base + lane*16
__device__ __forceinline__ void gload16(const void* g, void* l) {
  __builtin_amdgcn_global_load_lds((gvoid*)(uintptr_t)g,
                                   (lvoid*)(uint32_t)(uintptr_t)l,
                                   16, 0, 0);
}

__device__ __forceinline__ f32x4 mfma_16x16x32(bf16x8 a, bf16x8 b, f32x4 c) {
  return __builtin_amdgcn_mfma_f32_16x16x32_bf16(a, b, c, 0, 0, 0);
}

// ---------------- elementwise: fp32 -> bf16 convert ----------------
__global__ void k_cvt(const float* __restrict__ in, bf16* __restrict__ outp, int n4) {
  int i = blockIdx.x * 256 + threadIdx.x;
  if (i < n4) {
    float4 v = ((const float4*)in)[i];
    bf16x4 o;
    o[0] = (bf16)v.x; o[1] = (bf16)v.y; o[2] = (bf16)v.z; o[3] = (bf16)v.w;
    ((bf16x4*)outp)[i] = o;
  }
}

// ---------------- transpose fp32 [R,C] -> bf16 [C,R] ----------------
__launch_bounds__(256)
__global__ void k_transpose(const float* __restrict__ in, bf16* __restrict__ outp,
                            int R, int C) {
  __shared__ float tile[32][33];
  const int tx = threadIdx.x, ty = threadIdx.y;
  const int r0 = blockIdx.y * 32, c0 = blockIdx.x * 32;
#pragma unroll
  for (int i = 0; i < 32; i += 8)
    tile[ty + i][tx] = in[(size_t)(r0 + ty + i) * C + c0 + tx];
  __syncthreads();
#pragma unroll
  for (int i = 0; i < 32; i += 8)
    outp[(size_t)(c0 + ty + i) * R + r0 + tx] = (bf16)tile[tx][ty + i];
}

// ---------------- LayerNorm fp32 -> bf16, row = 1024 ----------------
__launch_bounds__(256)
__global__ void k_layernorm(const float* __restrict__ x, const float* __restrict__ w,
                            const float* __restrict__ bb, bf16* __restrict__ outp) {
  const int row = blockIdx.x;
  const int t = threadIdx.x;
  const float4 v = ((const float4*)(x + (size_t)row * EMB))[t];
  float s = v.x + v.y + v.z + v.w;
  __shared__ float red[4];
#pragma unroll
  for (int off = 32; off > 0; off >>= 1) s += __shfl_down(s, off, 64);
  if ((t & 63) == 0) red[t >> 6] = s;
  __syncthreads();
  const float mean = (red[0] + red[1] + red[2] + red[3]) * (1.0f / EMB);
  const float dx = v.x - mean, dy = v.y - mean, dz = v.z - mean, dw = v.w - mean;
  float ss = dx * dx + dy * dy + dz * dz + dw * dw;
  __syncthreads();
#pragma unroll
  for (int off = 32; off > 0; off >>= 1) ss += __shfl_down(ss, off, 64);
  if ((t & 63) == 0) red[t >> 6] = ss;
  __syncthreads();
  const float var = (red[0] + red[1] + red[2] + red[3]) * (1.0f / EMB);
  const float rstd = rsqrtf(var + 1e-5f);
  const float4 wv = ((const float4*)w)[t];
  const float4 bv = ((const float4*)bb)[t];
  bf16x4 o;
  o[0] = (bf16)(dx * rstd * wv.x + bv.x);
  o[1] = (bf16)(dy * rstd * wv.y + bv.y);
  o[2] = (bf16)(dz * rstd * wv.z + bv.z);
  o[3] = (bf16)(dw * rstd * wv.w + bv.w);
  *(bf16x4*)(outp + (size_t)row * EMB + t * 4) = o;
}

// ---------------- GEMM: C[M,N] = A[M,K] @ Bt[N,K]^T ----------------
// EPI 0: bf16 out. EPI 1: bf16 out = gelu(acc + bias). EPI 2: fp32 out = res + acc + bias.
template <int EPI>
__launch_bounds__(256)
__global__ void k_gemm(const bf16* __restrict__ A, const bf16* __restrict__ Bt,
                       int M, int N, int K,
                       bf16* __restrict__ outb, float* __restrict__ outf,
                       const float* __restrict__ res, const float* __restrict__ bias) {
  __shared__ __align__(16) bf16 sA[128 * 32];
  __shared__ __align__(16) bf16 sB[128 * 32];
  const int tid = threadIdx.x;
  const int wave = tid >> 6, lane = tid & 63;
  const int quad = lane >> 4, l16 = lane & 15;
  const int wm = wave >> 1, wn = wave & 1;
  const int bm = blockIdx.y, bn = blockIdx.x;

  f32x4 acc[4][4] = {};

  const int srow = wave * 16 + (lane >> 2);
  const int scol = (lane & 3) * 8;
  const bf16* Ag = A  + (size_t)(bm * 128 + srow) * K + scol;
  const bf16* Bg = Bt + (size_t)(bn * 128 + srow) * K + scol;
  bf16* sA0 = &sA[(wave * 16) * 32];
  bf16* sA1 = &sA[(wave * 16 + 64) * 32];
  bf16* sB0 = &sB[(wave * 16) * 32];
  bf16* sB1 = &sB[(wave * 16 + 64) * 32];

  const int nk = K >> 5;
  for (int kt = 0; kt < nk; ++kt) {
    gload16(Ag, sA0);
    gload16(Ag + (size_t)64 * K, sA1);
    gload16(Bg, sB0);
    gload16(Bg + (size_t)64 * K, sB1);
    Ag += 32; Bg += 32;
    __syncthreads();
    bf16x8 af[4], bfv[4];
    const bf16* pa = &sA[(wm * 64 + l16) * 32 + quad * 8];
    const bf16* pb = &sB[(wn * 64 + l16) * 32 + quad * 8];
#pragma unroll
    for (int i = 0; i < 4; ++i) af[i] = *(const bf16x8*)(pa + i * 16 * 32);
#pragma unroll
    for (int i = 0; i < 4; ++i) bfv[i] = *(const bf16x8*)(pb + i * 16 * 32);
#pragma unroll
    for (int i = 0; i < 4; ++i)
#pragma unroll
      for (int j = 0; j < 4; ++j)
        acc[i][j] = mfma_16x16x32(af[i], bfv[j], acc[i][j]);
    __syncthreads();
  }

  const int row0 = bm * 128 + wm * 64;
  const int col0 = bn * 128 + wn * 64;
#pragma unroll
  for (int j = 0; j < 4; ++j) {
    const int c = col0 + j * 16 + l16;
    const float bv = (EPI >= 1) ? bias[c] : 0.0f;
#pragma unroll
    for (int i = 0; i < 4; ++i) {
#pragma unroll
      for (int r = 0; r < 4; ++r) {
        const size_t rr = (size_t)(row0 + i * 16 + quad * 4 + r);
        float v = acc[i][j][r];
        if (EPI == 0) {
          outb[rr * N + c] = (bf16)v;
        } else if (EPI == 1) {
          v += bv;
          const float g = 0.5f * v *
              (1.0f + tanhf(0.7978845608028654f * (v + 0.044715f * v * v * v)));
          outb[rr * N + c] = (bf16)g;
        } else {
          outf[rr * N + c] = res[rr * N + c] + v + bv;
        }
      }
    }
  }
}

// ---------------- flash attention v2 ----------------
// 128 q-rows / block (wave w: rows q0+32w..+31, two 16-row m-subtiles),
// 64-key tiles. sK XOR-swizzled (gload16-compatible), sVt/sP stride-72.
// grid: (TQ/128, B*NH), block 256.
template <bool CAUSAL>
__launch_bounds__(256)
__global__ void k_attn(const bf16* __restrict__ Q, const bf16* __restrict__ Kg,
                       const bf16* __restrict__ Vg, bf16* __restrict__ Og,
                       int TQ, int TK) {
  __shared__ __align__(16) bf16 sK[64 * 64];    // [key][d], 16B chunks XOR-swizzled
  __shared__ __align__(16) bf16 sVt[64 * 72];   // [d][key], stride 72
  __shared__ __align__(16) bf16 sP[4][32 * 72]; // per wave, [q_local][key], stride 72
  const int tid = threadIdx.x;
  const int wave = tid >> 6, lane = tid & 63;
  const int quad = lane >> 4, l16 = lane & 15;
  const int b = blockIdx.y >> 4;   // NH == 16
  const int h = blockIdx.y & 15;
  const int qt = CAUSAL ? (gridDim.x - 1 - blockIdx.x) : blockIdx.x;
  const int q0 = qt * 128;
  const int qw = q0 + wave * 32;

  const bf16* Qbase = Q + (size_t)(b * TQ) * EMB + h * 64;
  const bf16* Kbase = Kg + (size_t)(b * TK) * EMB + h * 64;
  const bf16* Vbase = Vg + (size_t)(b * TK) * EMB + h * 64;

  // Q fragments: aq[m][c] covers rows qw+m*16+l16, d = c*32 + quad*8 .. +7
  bf16x8 aq[2][2];
#pragma unroll
  for (int m = 0; m < 2; ++m) {
    const bf16* qp = Qbase + (size_t)(qw + m * 16 + l16) * EMB + quad * 8;
    aq[m][0] = *(const bf16x8*)(qp);
    aq[m][1] = *(const bf16x8*)(qp + 32);
  }

  f32x4 oacc[2][4] = {};
  float m_[2][4], l_[2][4];
#pragma unroll
  for (int m = 0; m < 2; ++m)
#pragma unroll
    for (int r = 0; r < 4; ++r) { m_[m][r] = -1e30f; l_[m][r] = 0.0f; }

  const int srow = lane >> 3;      // 0..7 (row within 8-row staging group)
  const int schunk = lane & 7;     // physical 16B chunk
  bf16* sPw = &sP[wave][0];

  const float sc = 0.125f * 1.44269504088896f;  // 1/sqrt(64) * log2(e)
  const int nj = CAUSAL ? (q0 >> 6) + 2 : (TK >> 6);

  for (int j = 0; j < nj; ++j) {
    const int k0 = j * 64;
    // ---- stage K: 64 rows x 128B, chunk c stored at c^(row&7) ----
#pragma unroll
    for (int r2 = 0; r2 < 2; ++r2) {
      const int rowt = (wave + 4 * r2) * 8 + srow;
      const int gchunk = schunk ^ (rowt & 7);
      gload16(Kbase + (size_t)(k0 + rowt) * EMB + gchunk * 8,
              &sK[(wave + 4 * r2) * 8 * 64]);
    }
    // ---- stage V^T: wave handles d-chunk (wave+4r2), keys = lane ----
#pragma unroll
    for (int r2 = 0; r2 < 2; ++r2) {
      const int cv = wave + 4 * r2;
      const bf16x8 vv = *(const bf16x8*)(Vbase + (size_t)(k0 + lane) * EMB + cv * 8);
#pragma unroll
      for (int e = 0; e < 8; ++e) sVt[(cv * 8 + e) * 72 + lane] = vv[e];
    }
    __syncthreads();

    const bool active = !CAUSAL || (k0 <= qw + 31);
    if (active) {
#pragma unroll
      for (int m = 0; m < 2; ++m) {
        // ---- QK^T: scores s[kt][r] = S[row=m*16+quad*4+r][key=kt*16+l16] ----
        f32x4 s[4];
#pragma unroll
        for (int kt = 0; kt < 4; ++kt) {
          const int krow = kt * 16 + l16;
          const int p0 = (quad ^ (l16 & 7)) * 8;
          const int p1 = ((quad + 4) ^ (l16 & 7)) * 8;
          const bf16x8 bk0 = *(const bf16x8*)(&sK[krow * 64 + p0]);
          const bf16x8 bk1 = *(const bf16x8*)(&sK[krow * 64 + p1]);
          f32x4 z = {};
          z = mfma_16x16x32(aq[m][0], bk0, z);
          z = mfma_16x16x32(aq[m][1], bk1, z);
          s[kt] = z;
        }
        // ---- causal mask (raw domain) + row max ----
        float rowmax[4] = {-1e30f, -1e30f, -1e30f, -1e30f};
#pragma unroll
        for (int kt = 0; kt < 4; ++kt) {
          const int key = k0 + kt * 16 + l16;
#pragma unroll
          for (int r = 0; r < 4; ++r) {
            if (CAUSAL && key > qw + m * 16 + quad * 4 + r) s[kt][r] = -1e30f;
            rowmax[r] = fmaxf(rowmax[r], s[kt][r]);
          }
        }
#pragma unroll
        for (int off = 1; off < 16; off <<= 1)
#pragma unroll
          for (int r = 0; r < 4; ++r)
            rowmax[r] = fmaxf(rowmax[r], __shfl_xor(rowmax[r], off, 64));
        float alpha[4], nms[4], rs[4];
#pragma unroll
        for (int r = 0; r < 4; ++r) {
          const float mn = fmaxf(m_[m][r], rowmax[r]);
          alpha[r] = exp2f((m_[m][r] - mn) * sc);
          m_[m][r] = mn;
          nms[r] = -mn * sc;
          rs[r] = 0.0f;
        }
        // ---- P = exp2(s*sc - m*sc), row sums, write to sP ----
#pragma unroll
        for (int kt = 0; kt < 4; ++kt)
#pragma unroll
          for (int r = 0; r < 4; ++r) {
            const float pv = exp2f(fmaf(s[kt][r], sc, nms[r]));
            rs[r] += pv;
            sPw[(m * 16 + quad * 4 + r) * 72 + kt * 16 + l16] = (bf16)pv;
          }
#pragma unroll
        for (int off = 1; off < 16; off <<= 1)
#pragma unroll
          for (int r = 0; r < 4; ++r)
            rs[r] += __shfl_xor(rs[r], off, 64);
#pragma unroll
        for (int r = 0; r < 4; ++r) {
          l_[m][r] = l_[m][r] * alpha[r] + rs[r];
#pragma unroll
          for (int dt = 0; dt < 4; ++dt) oacc[m][dt][r] *= alpha[r];
        }
        // ---- PV ----
        const bf16x8 ap0 = *(const bf16x8*)(&sPw[(m * 16 + l16) * 72 + quad * 8]);
        const bf16x8 ap1 = *(const bf16x8*)(&sPw[(m * 16 + l16) * 72 + 32 + quad * 8]);
#pragma unroll
        for (int dt = 0; dt < 4; ++dt) {
          const bf16x8 bv0 = *(const bf16x8*)(&sVt[(dt * 16 + l16) * 72 + quad * 8]);
          const bf16x8 bv1 = *(const bf16x8*)(&sVt[(dt * 16 + l16) * 72 + 32 + quad * 8]);
          oacc[m][dt] = mfma_16x16x32(ap0, bv0, oacc[m][dt]);
          oacc[m][dt] = mfma_16x16x32(ap1, bv1, oacc[m][dt]);
        }
      }
    }
    __syncthreads();
  }

#pragma unroll
  for (int m = 0; m < 2; ++m)
#pragma unroll
    for (int r = 0; r < 4; ++r) {
      const float inv = 1.0f / l_[m][r];
      bf16* op = Og + (size_t)(b * TQ + qw + m * 16 + quad * 4 + r) * EMB + h * 64;
#pragma unroll
      for (int dt = 0; dt < 4; ++dt)
        op[dt * 16 + l16] = (bf16)(oacc[m][dt][r] * inv);
    }
}

// ---------------- host orchestration ----------------
extern "C" void kernel_launch(void* const* d_in, const int* in_sizes, int n_in,
                              void* d_out, int out_size, void* d_ws, size_t ws_size,
                              hipStream_t stream) {
  const float* enc  = (const float*)d_in[0];
  const float* dec  = (const float*)d_in[1];
  const float* ln1w = (const float*)d_in[2];
  const float* ln1b = (const float*)d_in[3];
  const float* ln2w = (const float*)d_in[4];
  const float* ln2b = (const float*)d_in[5];
  const float* ln3w = (const float*)d_in[6];
  const float* ln3b = (const float*)d_in[7];
  const float* Wq_s = (const float*)d_in[8];
  const float* Wk_s = (const float*)d_in[9];
  const float* Wv_s = (const float*)d_in[10];
  const float* Wo_s = (const float*)d_in[11];
  const float* bo_s = (const float*)d_in[12];
  const float* Wq_c = (const float*)d_in[13];
  const float* Wk_c = (const float*)d_in[14];
  const float* Wv_c = (const float*)d_in[15];
  const float* Wo_c = (const float*)d_in[16];
  const float* bo_c = (const float*)d_in[17];
  const float* W1   = (const float*)d_in[18];
  const float* b1   = (const float*)d_in[19];
  const float* W2   = (const float*)d_in[20];
  const float* b2   = (const float*)d_in[21];
  float* out = (float*)d_out;

  char* p = (char*)d_ws;
  auto take = [&](size_t bytes) {
    char* r = p;
    p += (bytes + 255) & ~(size_t)255;
    return (void*)r;
  };
  bf16* wqT  = (bf16*)take((size_t)EMB * EMB * 2);
  bf16* wkT  = (bf16*)take((size_t)EMB * EMB * 2);
  bf16* wvT  = (bf16*)take((size_t)EMB * EMB * 2);
  bf16* woT  = (bf16*)take((size_t)EMB * EMB * 2);
  bf16* w1T  = (bf16*)take((size_t)EMB * FFN * 2);
  bf16* w2T  = (bf16*)take((size_t)FFN * EMB * 2);
  bf16* encb = (bf16*)take((size_t)BATCH * SENC * EMB * 2);
  float* xbuf = (float*)take((size_t)MTOK * EMB * 4);
  bf16* nx = (bf16*)take((size_t)MTOK * EMB * 2);
  bf16* qb = (bf16*)take((size_t)MTOK * EMB * 2);
  bf16* kb = (bf16*)take((size_t)MTOK * EMB * 2);
  bf16* vb = (bf16*)take((size_t)MTOK * EMB * 2);
  bf16* ab = (bf16*)take((size_t)MTOK * EMB * 2);
  bf16* hb = (bf16*)take((size_t)MTOK * FFN * 2);
  if ((size_t)((char*)p - (char*)d_ws) > ws_size) return;  // ws too small: fail loudly

  // encoder -> bf16 (once); x = decoder_input
  {
    const int n4 = BATCH * SENC * EMB / 4;
    k_cvt<<<(n4 + 255) / 256, 256, 0, stream>>>(enc, encb, n4);
  }
  hipMemcpyAsync(xbuf, dec, (size_t)MTOK * EMB * 4, hipMemcpyDeviceToDevice, stream);

  auto trans = [&](const float* w, bf16* wt, int R, int C) {
    k_transpose<<<dim3(C / 32, R / 32), dim3(32, 8), 0, stream>>>(w, wt, R, C);
  };
  auto gemm0 = [&](const bf16* Ap, const bf16* Btp, bf16* op, int M, int N, int K) {
    k_gemm<0><<<dim3(N / 128, M / 128), 256, 0, stream>>>(Ap, Btp, M, N, K, op,
                                                          nullptr, nullptr, nullptr);
  };
  auto gemm_gelu = [&](const bf16* Ap, const bf16* Btp, bf16* op, const float* bi,
                       int M, int N, int K) {
    k_gemm<1><<<dim3(N / 128, M / 128), 256, 0, stream>>>(Ap, Btp, M, N, K, op,
                                                          nullptr, nullptr, bi);
  };
  auto gemm_res = [&](const bf16* Ap, const bf16* Btp, float* op, const float* rs,
                      const float* bi, int M, int N, int K) {
    k_gemm<2><<<dim3(N / 128, M / 128), 256, 0, stream>>>(Ap, Btp, M, N, K, nullptr,
                                                          op, rs, bi);
  };

  for (int l = 0; l < LAYERS; ++l) {
    const size_t wofs = (size_t)l * EMB * EMB;
    // ---- self attention ----
    k_layernorm<<<MTOK, 256, 0, stream>>>(xbuf, ln1w + l * EMB, ln1b + l * EMB, nx);
    trans(Wq_s + wofs, wqT, EMB, EMB);
    trans(Wk_s + wofs, wkT, EMB, EMB);
    trans(Wv_s + wofs, wvT, EMB, EMB);
    trans(Wo_s + wofs, woT, EMB, EMB);
    gemm0(nx, wqT, qb, MTOK, EMB, EMB);
    gemm0(nx, wkT, kb, MTOK, EMB, EMB);
    gemm0(nx, wvT, vb, MTOK, EMB, EMB);
    k_attn<true><<<dim3(TDEC / 128, BATCH * NH), 256, 0, stream>>>(qb, kb, vb, ab,
                                                                   TDEC, TDEC);
    gemm_res(ab, woT, xbuf, xbuf, bo_s + l * EMB, MTOK, EMB, EMB);

    // ---- cross attention ----
    k_layernorm<<<MTOK, 256, 0, stream>>>(xbuf, ln2w + l * EMB, ln2b + l * EMB, nx);
    trans(Wq_c + wofs, wqT, EMB, EMB);
    trans(Wk_c + wofs, wkT, EMB, EMB);
    trans(Wv_c + wofs, wvT, EMB, EMB);
    trans(Wo_c + wofs, woT, EMB, EMB);
    gemm0(nx, wqT, qb, MTOK, EMB, EMB);
    gemm0(encb, wkT, kb, BATCH * SENC, EMB, EMB);
    gemm0(encb, wvT, vb, BATCH * SENC, EMB, EMB);
    k_attn<false><<<dim3(TDEC / 128, BATCH * NH), 256, 0, stream>>>(qb, kb, vb, ab,
                                                                    TDEC, SENC);
    gemm_res(ab, woT, xbuf, xbuf, bo_c + l * EMB, MTOK, EMB, EMB);

    // ---- FFN ----
    k_layernorm<<<MTOK, 256, 0, stream>>>(xbuf, ln3w + l * EMB, ln3b + l * EMB, nx);
    trans(W1 + (size_t)l * EMB * FFN, w1T, EMB, FFN);
    trans(W2 + (size_t)l * FFN * EMB, w2T, FFN, EMB);
    gemm_gelu(nx, w1T, hb, b1 + (size_t)l * FFN, MTOK, FFN, EMB);
    float* fout = (l == LAYERS - 1) ? out : xbuf;
    gemm_res(hb, w2T, fout, xbuf, b2 + (size_t)l * EMB, MTOK, EMB, FFN);
  }
}